// Round 17
// baseline (123.245 us; speedup 1.0000x reference)
//
#include <hip/hip_runtime.h>
#include <hip/hip_bf16.h>

typedef __attribute__((ext_vector_type(8)))  short short8;
typedef __attribute__((ext_vector_type(4)))  float f32x4;
typedef __attribute__((ext_vector_type(16))) float f32x16;

constexpr float EPSf = 1e-5f;

__device__ __forceinline__ unsigned short f2bf(float f) {
    union { float f; unsigned int i; } x; x.f = f;
    unsigned int r = x.i + 0x7fffu + ((x.i >> 16) & 1u);
    return (unsigned short)(r >> 16);
}
__device__ __forceinline__ unsigned int pk2bf(float lo, float hi) {
    union { __hip_bfloat162 h; unsigned int u; } z;
    z.h = __float22bfloat162_rn(make_float2(lo, hi));
    return z.u;
}

// ---------------- LDS layout: 81920 bytes, PT=16 points/block ----------------
// Region A 0..65535: per-pt 4KB: P1 [16r][64c] (0..2047), P2 [64c][16r] (2048..4095)
//                    FLAT [2048 k] overlays whole 4KB (wave-private read-then-write)
// Region B 65536..81919 (16KB), time-multiplexed (barrier-fenced):
//   FBF  [16 pt][64 c] bf16 (2KB)            — prologue write, stage-A read
//   T1   [8 w][2 pp][32 s][16 r] bf16 (16KB) — stage B (per wave AND per point)
//   PART [2 kh][4 mt][16 pt][16 o] f32 (8KB) — stage C (overlays T1)
__device__ __forceinline__ int P1a(int pt, int r, int c) {
    return pt*4096 + ((r*128 + c*2) ^ (((r ^ pt) & 7) << 4));
}
__device__ __forceinline__ int P2a(int pt, int c, int r) {
    return pt*4096 + 2048 + ((c*32 + r*2) ^ (((((c>>2)&1) ^ (pt&7))) << 4));
}
__device__ __forceinline__ int FTa(int pt, int k) {
    return pt*4096 + ((k*2) ^ (((pt ^ (k>>6)) & 7) << 4));
}
__device__ __forceinline__ int FBa(int pt, int c) {
    return 65536 + pt*128 + ((c*2) ^ ((pt&7) << 4));
}
__device__ __forceinline__ int T1a(int w, int pp, int s, int r) {
    return 65536 + w*2048 + pp*1024 + ((s*32 + r*2) ^ (((s>>2)&1) << 4));
}
__device__ __forceinline__ int PARTw(int kh, int mt, int pt, int g) {   // f32x4 write
    return 65536 + ((kh*4 + mt) << 10) + pt*64 + ((g ^ ((pt>>1)&3)) << 4);
}
__device__ __forceinline__ int PARTr(int kh, int mt, int pt, int o16) { // f32 read
    return 65536 + ((kh*4 + mt) << 10) + pt*64
         + ((((o16>>2) ^ ((pt>>1)&3)) << 4) | ((o16&3) << 2));
}

// ---- prep: fold BN into bf16 weights, MFMA-fragment-linear order ----
// w1 rows are PERMUTED so the stage-A C-fragment's 4 rows/lane are LDS-contiguous:
//   o < 1024  (param1, o = c*16+r):  m = r*64 + c      (q-quad = 4 consecutive c)
//   o >= 1024 (param2, o2 = r*64+c): m = 1024 + c*16+r (q-quad = 4 consecutive r)
// sh1 is stored at the permuted index m.
__global__ void prep_kernel(const float* __restrict__ w1,
                            const float* __restrict__ g1, const float* __restrict__ b1,
                            const float* __restrict__ m1, const float* __restrict__ v1,
                            const float* __restrict__ w2,
                            const float* __restrict__ g2, const float* __restrict__ b2,
                            const float* __restrict__ m2, const float* __restrict__ v2,
                            unsigned short* __restrict__ w1f, unsigned short* __restrict__ w2f,
                            float* __restrict__ sh1, float* __restrict__ sh2) {
    int idx = blockIdx.x * 256 + threadIdx.x;
    if (idx < 2048*64) {
        int o = idx >> 6, cin = idx & 63;
        float inv = g1[o] * rsqrtf(v1[o] + EPSf);
        int m;
        if (o < 1024) { m = (o & 15)*64 + (o >> 4); }
        else          { int o2 = o - 1024; m = 1024 + (o2 & 63)*16 + (o2 >> 6); }
        int i = m >> 4, row = m & 15;
        int kk = cin >> 5, gg = (cin >> 3) & 3, j = cin & 7;
        w1f[(((i*2 + kk)*64) + gg*16 + row)*8 + j] = f2bf(w1[idx] * inv);

        int o2w = idx >> 11, k = idx & 2047;
        float inv2 = g2[o2w] * rsqrtf(v2[o2w] + EPSf);
        int ks = k >> 5, mt = o2w >> 4, gk = (k >> 3) & 3, j2 = k & 7;
        w2f[(((ks*4 + mt)*64) + gk*16 + (o2w & 15))*8 + j2] = f2bf(w2[idx] * inv2);
    }
    if (idx < 2048) {
        int o = idx;
        float inv = g1[o] * rsqrtf(v1[o] + EPSf);
        float val = b1[o] - m1[o] * inv;
        int m;
        if (o < 1024) { m = (o & 15)*64 + (o >> 4); }
        else          { int o2 = o - 1024; m = 1024 + (o2 & 63)*16 + (o2 >> 6); }
        sh1[m] = val;
    }
    if (idx < 64) sh2[idx] = b2[idx] - m2[idx] * (g2[idx] * rsqrtf(v2[idx] + EPSf));
}

// waves_per_eu(4,4): LDS (80KB -> 2 blocks/CU) caps occupancy at 4 waves/SIMD;
// telling the allocator unlocks the true 128-VGPR budget so the interleaved
// stage B (4 simultaneous f32x16 accumulators) can allocate instead of spill.
__global__ __attribute__((amdgpu_flat_work_group_size(512, 512), amdgpu_waves_per_eu(4, 4)))
void dyn_mfma(
    const float* __restrict__ pre, const float* __restrict__ feat,
    const unsigned short* __restrict__ w1f, const unsigned short* __restrict__ w2f,
    const float* __restrict__ sh1, const float* __restrict__ sh2,
    const float* __restrict__ ln1g, const float* __restrict__ ln1b,
    const float* __restrict__ ln2g, const float* __restrict__ ln2b,
    float* __restrict__ out)
{
    __shared__ __align__(16) unsigned char smem[81920];
    unsigned short* sm16 = (unsigned short*)smem;

    const int tid = threadIdx.x;
    const int w  = tid >> 6, l = tid & 63;
    const int lr = l & 15, g = l >> 4;      // 16-lane MFMA frame
    const int c32 = l & 31, hi = l >> 5;    // 32-lane MFMA frame

    const int p0 = blockIdx.x * 16;
    const int b  = p0 >> 12, n0 = p0 & 4095;

    const f32x4 zz4 = {0.f, 0.f, 0.f, 0.f};
    const f32x16 zz16 = {};

    // ---- issue point-0 pre loads (latency hides under prologue) ----
    const float* pbase0 = pre + (size_t)b*8388608 + (size_t)(n0 + w*2 + 0)*32;
    const float* pbase1 = pbase0 + 32;
    float pf[2][2][8];
    #pragma unroll
    for (int kk = 0; kk < 2; ++kk)
        #pragma unroll
        for (int nt = 0; nt < 2; ++nt)
            #pragma unroll
            for (int j = 0; j < 8; ++j)
                pf[kk][nt][j] = pbase0[(size_t)(kk*32 + g*8 + j)*131072 + nt*16 + lr];

    // ---- prologue: features -> FBF bf16 (16 real points) ----
    {
        int c = tid >> 3, pj = tid & 7;
        const float* fb = feat + ((size_t)(b*64 + c))*4096 + n0 + pj;
        sm16[FBa(pj,     c) >> 1] = f2bf(fb[0]);
        sm16[FBa(pj + 8, c) >> 1] = f2bf(fb[8]);
    }

    // ---- pack point-0 -> pb0 (16 regs) ----
    short8 pb0[2][2], pb1[2][2];
    #pragma unroll
    for (int kk = 0; kk < 2; ++kk)
        #pragma unroll
        for (int nt = 0; nt < 2; ++nt) {
            union { unsigned int u[4]; short8 s; } z;
            #pragma unroll
            for (int d = 0; d < 4; ++d)
                z.u[d] = pk2bf(pf[kk][nt][2*d], pf[kk][nt][2*d + 1]);
            pb0[kk][nt] = z.s;
        }
    // pf1 is issued AFTER this barrier (hipcc drains vmcnt(0) at s_barrier;
    // issuing after lets it genuinely fly under stage A — R15 win).
    __syncthreads();

    // ---- issue point-1 pre loads (in flight for real under stage A) ----
    float pf1[2][2][8];
    #pragma unroll
    for (int kk = 0; kk < 2; ++kk)
        #pragma unroll
        for (int nt = 0; nt < 2; ++nt)
            #pragma unroll
            for (int j = 0; j < 8; ++j)
                pf1[kk][nt][j] = pbase1[(size_t)(kk*32 + g*8 + j)*131072 + nt*16 + lr];

    // ---------------- Stage A: h = relu(w1f @ f + sh1) -> P1/P2 (pf1 in flight) --------
    {
        short8 bf0 = *(const short8*)&smem[FBa(lr, g*8)];
        short8 bf1 = *(const short8*)&smem[FBa(lr, 32 + g*8)];
        const unsigned short* w1p = w1f + ((size_t)(w*32)*64 + l)*8;
        #pragma unroll 8
        for (int ii = 0; ii < 16; ++ii) {
            short8 a0 = *(const short8*)(w1p + (ii*2 + 0)*512);
            short8 a1 = *(const short8*)(w1p + (ii*2 + 1)*512);
            f32x4 acc = __builtin_amdgcn_mfma_f32_16x16x32_bf16(a0, bf0, zz4, 0, 0, 0);
            acc = __builtin_amdgcn_mfma_f32_16x16x32_bf16(a1, bf1, acc, 0, 0, 0);
            const int i = w*16 + ii;
            f32x4 shv = *(const f32x4*)(sh1 + i*16 + g*4);
            float h0 = fmaxf(acc[0] + shv[0], 0.f);
            float h1 = fmaxf(acc[1] + shv[1], 0.f);
            float h2 = fmaxf(acc[2] + shv[2], 0.f);
            float h3 = fmaxf(acc[3] + shv[3], 0.f);
            uint2 hv; hv.x = pk2bf(h0, h1); hv.y = pk2bf(h2, h3);
            if (w < 4) {
                *(uint2*)&smem[P1a(lr, i >> 2, (i & 3)*16 + g*4)] = hv;
            } else {
                *(uint2*)&smem[P2a(lr, i - 64, g*4)] = hv;
            }
        }
    }
    // ---- pack point-1 -> pb1 (pf1 drains here, hidden by stage A above) ----
    #pragma unroll
    for (int kk = 0; kk < 2; ++kk)
        #pragma unroll
        for (int nt = 0; nt < 2; ++nt) {
            union { unsigned int u[4]; short8 s; } z;
            #pragma unroll
            for (int d = 0; d < 4; ++d)
                z.u[d] = pk2bf(pf1[kk][nt][2*d], pf1[kk][nt][2*d + 1]);
            pb1[kk][nt] = z.s;
        }
    __syncthreads();

    // ---------------- Stage B: 2 points per wave, phase-interleaved (2x ILP) -----------
    {
        const int pt0 = w*2 + 0, pt1 = w*2 + 1;
        f32x4 l1g = *(const f32x4*)(ln1g + g*4);
        f32x4 l1b = *(const f32x4*)(ln1b + g*4);

        // phase 1: GEMM1 both points (independent chains)
        short8 a1f0_0 = *(const short8*)&smem[P1a(pt0, lr, g*8)];
        short8 a1f1_0 = *(const short8*)&smem[P1a(pt0, lr, 32 + g*8)];
        short8 a1f0_1 = *(const short8*)&smem[P1a(pt1, lr, g*8)];
        short8 a1f1_1 = *(const short8*)&smem[P1a(pt1, lr, 32 + g*8)];
        f32x4 acc1_0[2], acc1_1[2];
        #pragma unroll
        for (int nt = 0; nt < 2; ++nt) {
            f32x4 a = __builtin_amdgcn_mfma_f32_16x16x32_bf16(a1f0_0, pb0[0][nt], zz4, 0, 0, 0);
            acc1_0[nt] = __builtin_amdgcn_mfma_f32_16x16x32_bf16(a1f1_0, pb0[1][nt], a, 0, 0, 0);
            f32x4 c = __builtin_amdgcn_mfma_f32_16x16x32_bf16(a1f0_1, pb1[0][nt], zz4, 0, 0, 0);
            acc1_1[nt] = __builtin_amdgcn_mfma_f32_16x16x32_bf16(a1f1_1, pb1[1][nt], c, 0, 0, 0);
        }

        // phase 2: LN1 both points -> T1[w][pp]
        auto ln1_store = [&](const f32x4 (&acc1)[2], int pp) {
            #pragma unroll
            for (int nt = 0; nt < 2; ++nt) {
                float s0 = acc1[nt][0] + acc1[nt][1] + acc1[nt][2] + acc1[nt][3];
                float q0 = acc1[nt][0]*acc1[nt][0] + acc1[nt][1]*acc1[nt][1]
                         + acc1[nt][2]*acc1[nt][2] + acc1[nt][3]*acc1[nt][3];
                s0 += __shfl_xor(s0, 16); s0 += __shfl_xor(s0, 32);
                q0 += __shfl_xor(q0, 16); q0 += __shfl_xor(q0, 32);
                float mu = s0 * 0.0625f;
                float rs = rsqrtf(q0 * 0.0625f - mu*mu + EPSf);
                float v0 = fmaxf((acc1[nt][0] - mu)*rs*l1g[0] + l1b[0], 0.f);
                float v1 = fmaxf((acc1[nt][1] - mu)*rs*l1g[1] + l1b[1], 0.f);
                float v2 = fmaxf((acc1[nt][2] - mu)*rs*l1g[2] + l1b[2], 0.f);
                float v3 = fmaxf((acc1[nt][3] - mu)*rs*l1g[3] + l1b[3], 0.f);
                uint2 dd; dd.x = pk2bf(v0, v1); dd.y = pk2bf(v2, v3);
                *(uint2*)&smem[T1a(w, pp, nt*16 + lr, g*4)] = dd;
            }
        };
        ln1_store(acc1_0, 0);
        ln1_store(acc1_1, 1);

        // phase 3: GEMM2 both points (4 independent 32x32x16 MFMAs)
        short8 bt1_0  = *(const short8*)&smem[T1a(w, 0, c32, hi*8)];
        short8 a2f0_0 = *(const short8*)&smem[P2a(pt0, c32, hi*8)];
        short8 a2f1_0 = *(const short8*)&smem[P2a(pt0, 32 + c32, hi*8)];
        short8 bt1_1  = *(const short8*)&smem[T1a(w, 1, c32, hi*8)];
        short8 a2f0_1 = *(const short8*)&smem[P2a(pt1, c32, hi*8)];
        short8 a2f1_1 = *(const short8*)&smem[P2a(pt1, 32 + c32, hi*8)];
        f32x16 A0 = __builtin_amdgcn_mfma_f32_32x32x16_bf16(a2f0_0, bt1_0, zz16, 0, 0, 0);
        f32x16 B0 = __builtin_amdgcn_mfma_f32_32x32x16_bf16(a2f1_0, bt1_0, zz16, 0, 0, 0);
        f32x16 A1 = __builtin_amdgcn_mfma_f32_32x32x16_bf16(a2f0_1, bt1_1, zz16, 0, 0, 0);
        f32x16 B1 = __builtin_amdgcn_mfma_f32_32x32x16_bf16(a2f1_1, bt1_1, zz16, 0, 0, 0);

        // phase 4: LN2 + FLAT writes, both points
        auto ln2_store = [&](const f32x16 &acc2a, const f32x16 &acc2b, int pt) {
            float sm2 = 0.f, sq2 = 0.f;
            #pragma unroll
            for (int e = 0; e < 16; ++e) { float v = acc2a[e]; sm2 += v; sq2 += v*v; }
            #pragma unroll
            for (int e = 0; e < 16; ++e) { float v = acc2b[e]; sm2 += v; sq2 += v*v; }
            sm2 += __shfl_xor(sm2, 32); sq2 += __shfl_xor(sq2, 32);
            float mu2 = sm2 * (1.0f/64.0f);
            float rs2 = rsqrtf(sq2 * (1.0f/64.0f) - mu2*mu2 + EPSf);
            #pragma unroll
            for (int qh = 0; qh < 4; ++qh) {
                int c0 = qh*8 + hi*4;
                f32x4 gq = *(const f32x4*)(ln2g + c0);
                f32x4 bq = *(const f32x4*)(ln2b + c0);
                float t0 = fmaxf((acc2a[qh*4 + 0] - mu2)*rs2*gq[0] + bq[0], 0.f);
                float t1 = fmaxf((acc2a[qh*4 + 1] - mu2)*rs2*gq[1] + bq[1], 0.f);
                float t2 = fmaxf((acc2a[qh*4 + 2] - mu2)*rs2*gq[2] + bq[2], 0.f);
                float t3 = fmaxf((acc2a[qh*4 + 3] - mu2)*rs2*gq[3] + bq[3], 0.f);
                uint2 dd; dd.x = pk2bf(t0, t1); dd.y = pk2bf(t2, t3);
                *(uint2*)&smem[FTa(pt, c32*64 + c0)] = dd;
            }
            #pragma unroll
            for (int qh = 0; qh < 4; ++qh) {
                int c0 = 32 + qh*8 + hi*4;
                f32x4 gq = *(const f32x4*)(ln2g + c0);
                f32x4 bq = *(const f32x4*)(ln2b + c0);
                float t0 = fmaxf((acc2b[qh*4 + 0] - mu2)*rs2*gq[0] + bq[0], 0.f);
                float t1 = fmaxf((acc2b[qh*4 + 1] - mu2)*rs2*gq[1] + bq[1], 0.f);
                float t2 = fmaxf((acc2b[qh*4 + 2] - mu2)*rs2*gq[2] + bq[2], 0.f);
                float t3 = fmaxf((acc2b[qh*4 + 3] - mu2)*rs2*gq[3] + bq[3], 0.f);
                uint2 dd; dd.x = pk2bf(t0, t1); dd.y = pk2bf(t2, t3);
                *(uint2*)&smem[FTa(pt, c32*64 + c0)] = dd;
            }
        };
        ln2_store(A0, B0, pt0);
        ln2_store(A1, B1, pt1);
    }
    __syncthreads();

    // ---------------- Stage C: w2f @ flat, 2 k-halves x 4 m-tiles, dual acc chains ------
    {
        const int kh = w >> 2, mt = w & 3;
        f32x4 accA = zz4, accB = zz4;
        #pragma unroll 4
        for (int t = 0; t < 32; t += 2) {
            const int ks = kh*32 + t;
            short8 bfl0 = *(const short8*)&smem[FTa(lr, ks*32 + g*8)];
            short8 af0  = *(const short8*)(w2f + ((size_t)(ks*4 + mt)*64 + l)*8);
            short8 bfl1 = *(const short8*)&smem[FTa(lr, (ks+1)*32 + g*8)];
            short8 af1  = *(const short8*)(w2f + ((size_t)((ks+1)*4 + mt)*64 + l)*8);
            accA = __builtin_amdgcn_mfma_f32_16x16x32_bf16(af0, bfl0, accA, 0, 0, 0);
            accB = __builtin_amdgcn_mfma_f32_16x16x32_bf16(af1, bfl1, accB, 0, 0, 0);
        }
        f32x4 acc = accA + accB;
        *(f32x4*)&smem[PARTw(kh, mt, lr, g)] = acc;   // PART overlays T1 (dead)
    }
    __syncthreads();
    // reduce 2 partials; epilogue: relu(affine) + residual relu (2 points/thread)
    {
        const int ro = tid >> 3, rp = tid & 7;
        const int mt2 = ro >> 4, o16 = ro & 15;
        const float sh2v = sh2[ro];
        #pragma unroll
        for (int ph = 0; ph < 2; ++ph) {
            const int pt = rp + ph*8;
            float s = *(const float*)&smem[PARTr(0, mt2, pt, o16)]
                    + *(const float*)&smem[PARTr(1, mt2, pt, o16)];
            float y = fmaxf(s + sh2v, 0.f);
            size_t oidx = ((size_t)(b*64 + ro))*4096 + n0 + pt;
            out[oidx] = fmaxf(y + feat[oidx], 0.f);
        }
    }
}

extern "C" void kernel_launch(void* const* d_in, const int* in_sizes, int n_in,
                              void* d_out, int out_size, void* d_ws, size_t ws_size,
                              hipStream_t stream) {
    (void)in_sizes; (void)n_in; (void)out_size; (void)ws_size;
    const float* pre  = (const float*)d_in[0];
    const float* feat = (const float*)d_in[1];
    const float* w1   = (const float*)d_in[2];
    const float* bn1g = (const float*)d_in[3];
    const float* bn1b = (const float*)d_in[4];
    const float* bn1m = (const float*)d_in[5];
    const float* bn1v = (const float*)d_in[6];
    const float* ln1g = (const float*)d_in[7];
    const float* ln1b = (const float*)d_in[8];
    const float* ln2g = (const float*)d_in[9];
    const float* ln2b = (const float*)d_in[10];
    const float* w2   = (const float*)d_in[11];
    const float* bn2g = (const float*)d_in[12];
    const float* bn2b = (const float*)d_in[13];
    const float* bn2m = (const float*)d_in[14];
    const float* bn2v = (const float*)d_in[15];
    float* out = (float*)d_out;

    unsigned short* w1f = (unsigned short*)d_ws;          // 2048*64 bf16
    unsigned short* w2f = w1f + 2048*64;                  // 64*2048 bf16
    float* sh1 = (float*)(w2f + 64*2048);                 // 2048 f32 (permuted index)
    float* sh2 = sh1 + 2048;                              // 64 f32

    prep_kernel<<<512, 256, 0, stream>>>(w1, bn1g, bn1b, bn1m, bn1v,
                                         w2, bn2g, bn2b, bn2m, bn2v,
                                         w1f, w2f, sh1, sh2);
    dyn_mfma<<<2048, 512, 0, stream>>>(pre, feat, w1f, w2f, sh1, sh2,
                                       ln1g, ln1b, ln2g, ln2b, out);
}

// Round 18
// 112.710 us; speedup vs baseline: 1.0935x; 1.0935x over previous
//
#include <hip/hip_runtime.h>
#include <hip/hip_bf16.h>

typedef __attribute__((ext_vector_type(8)))  short short8;
typedef __attribute__((ext_vector_type(4)))  float f32x4;
typedef __attribute__((ext_vector_type(16))) float f32x16;

constexpr float EPSf = 1e-5f;

__device__ __forceinline__ unsigned short f2bf(float f) {
    union { float f; unsigned int i; } x; x.f = f;
    unsigned int r = x.i + 0x7fffu + ((x.i >> 16) & 1u);
    return (unsigned short)(r >> 16);
}
__device__ __forceinline__ unsigned int pk2bf(float lo, float hi) {
    union { __hip_bfloat162 h; unsigned int u; } z;
    z.h = __float22bfloat162_rn(make_float2(lo, hi));
    return z.u;
}

// ---------------- LDS layout: 73728 bytes, PT=16 points/block ----------------
// Region A 0..65535: per-pt 4KB: P1 [16r][64c] (0..2047), P2 [64c][16r] (2048..4095)
//                    FLAT [2048 k] overlays whole 4KB (wave-private read-then-write)
// Region B 65536..73727 (8KB), time-multiplexed:
//   FBF  [16 pt][64 c] bf16 (2KB)       — prologue write, stage-A read
//   T1   [8 w][32 s][16 r] bf16 (8KB)   — stage B (overlays FBF after post-A barrier)
//   PART [2 kh][4 mt][16 pt][16 o] f32 (8KB) — stage C (overlays T1)
__device__ __forceinline__ int P1a(int pt, int r, int c) {
    return pt*4096 + ((r*128 + c*2) ^ (((r ^ pt) & 7) << 4));
}
__device__ __forceinline__ int P2a(int pt, int c, int r) {
    return pt*4096 + 2048 + ((c*32 + r*2) ^ (((((c>>2)&1) ^ (pt&7))) << 4));
}
__device__ __forceinline__ int FTa(int pt, int k) {
    return pt*4096 + ((k*2) ^ (((pt ^ (k>>6)) & 7) << 4));
}
__device__ __forceinline__ int FBa(int pt, int c) {
    return 65536 + pt*128 + ((c*2) ^ ((pt&7) << 4));
}
__device__ __forceinline__ int T1a(int w, int s, int r) {
    return 65536 + w*1024 + ((s*32 + r*2) ^ (((s>>2)&1) << 4));
}
__device__ __forceinline__ int PARTw(int kh, int mt, int pt, int g) {   // f32x4 write
    return 65536 + ((kh*4 + mt) << 10) + pt*64 + ((g ^ ((pt>>1)&3)) << 4);
}
__device__ __forceinline__ int PARTr(int kh, int mt, int pt, int o16) { // f32 read
    return 65536 + ((kh*4 + mt) << 10) + pt*64
         + ((((o16>>2) ^ ((pt>>1)&3)) << 4) | ((o16&3) << 2));
}

// ---- prep: fold BN into bf16 weights, MFMA-fragment-linear order ----
// w1 rows are PERMUTED so the stage-A C-fragment's 4 rows/lane are LDS-contiguous:
//   o < 1024  (param1, o = c*16+r):  m = r*64 + c      (q-quad = 4 consecutive c)
//   o >= 1024 (param2, o2 = r*64+c): m = 1024 + c*16+r (q-quad = 4 consecutive r)
// sh1 is stored at the permuted index m.
__global__ void prep_kernel(const float* __restrict__ w1,
                            const float* __restrict__ g1, const float* __restrict__ b1,
                            const float* __restrict__ m1, const float* __restrict__ v1,
                            const float* __restrict__ w2,
                            const float* __restrict__ g2, const float* __restrict__ b2,
                            const float* __restrict__ m2, const float* __restrict__ v2,
                            unsigned short* __restrict__ w1f, unsigned short* __restrict__ w2f,
                            float* __restrict__ sh1, float* __restrict__ sh2) {
    int idx = blockIdx.x * 256 + threadIdx.x;
    if (idx < 2048*64) {
        int o = idx >> 6, cin = idx & 63;
        float inv = g1[o] * rsqrtf(v1[o] + EPSf);
        int m;
        if (o < 1024) { m = (o & 15)*64 + (o >> 4); }
        else          { int o2 = o - 1024; m = 1024 + (o2 & 63)*16 + (o2 >> 6); }
        int i = m >> 4, row = m & 15;
        int kk = cin >> 5, gg = (cin >> 3) & 3, j = cin & 7;
        w1f[(((i*2 + kk)*64) + gg*16 + row)*8 + j] = f2bf(w1[idx] * inv);

        int o2w = idx >> 11, k = idx & 2047;
        float inv2 = g2[o2w] * rsqrtf(v2[o2w] + EPSf);
        int ks = k >> 5, mt = o2w >> 4, gk = (k >> 3) & 3, j2 = k & 7;
        w2f[(((ks*4 + mt)*64) + gk*16 + (o2w & 15))*8 + j2] = f2bf(w2[idx] * inv2);
    }
    if (idx < 2048) {
        int o = idx;
        float inv = g1[o] * rsqrtf(v1[o] + EPSf);
        float val = b1[o] - m1[o] * inv;
        int m;
        if (o < 1024) { m = (o & 15)*64 + (o >> 4); }
        else          { int o2 = o - 1024; m = 1024 + (o2 & 63)*16 + (o2 >> 6); }
        sh1[m] = val;
    }
    if (idx < 64) sh2[idx] = b2[idx] - m2[idx] * (g2[idx] * rsqrtf(v2[idx] + EPSf));
}

__global__ __launch_bounds__(512, 4) void dyn_mfma(
    const float* __restrict__ pre, const float* __restrict__ feat,
    const unsigned short* __restrict__ w1f, const unsigned short* __restrict__ w2f,
    const float* __restrict__ sh1, const float* __restrict__ sh2,
    const float* __restrict__ ln1g, const float* __restrict__ ln1b,
    const float* __restrict__ ln2g, const float* __restrict__ ln2b,
    float* __restrict__ out)
{
    __shared__ __align__(16) unsigned char smem[73728];
    unsigned short* sm16 = (unsigned short*)smem;

    const int tid = threadIdx.x;
    const int w  = tid >> 6, l = tid & 63;
    const int lr = l & 15, g = l >> 4;      // 16-lane MFMA frame
    const int c32 = l & 31, hi = l >> 5;    // 32-lane MFMA frame

    const int p0 = blockIdx.x * 16;
    const int b  = p0 >> 12, n0 = p0 & 4095;

    const f32x4 zz4 = {0.f, 0.f, 0.f, 0.f};
    const f32x16 zz16 = {};

    // ---- issue point-0 pre loads (latency hides under prologue) ----
    const float* pbase0 = pre + (size_t)b*8388608 + (size_t)(n0 + w*2 + 0)*32;
    const float* pbase1 = pbase0 + 32;
    float pf[2][2][8];
    #pragma unroll
    for (int kk = 0; kk < 2; ++kk)
        #pragma unroll
        for (int nt = 0; nt < 2; ++nt)
            #pragma unroll
            for (int j = 0; j < 8; ++j)
                pf[kk][nt][j] = pbase0[(size_t)(kk*32 + g*8 + j)*131072 + nt*16 + lr];

    // ---- prologue: features -> FBF bf16 (16 real points) ----
    {
        int c = tid >> 3, pj = tid & 7;
        const float* fb = feat + ((size_t)(b*64 + c))*4096 + n0 + pj;
        sm16[FBa(pj,     c) >> 1] = f2bf(fb[0]);
        sm16[FBa(pj + 8, c) >> 1] = f2bf(fb[8]);
    }

    // ---- pack point-0 -> pb0 (16 regs) ----
    short8 pb0[2][2], pb1[2][2];
    #pragma unroll
    for (int kk = 0; kk < 2; ++kk)
        #pragma unroll
        for (int nt = 0; nt < 2; ++nt) {
            union { unsigned int u[4]; short8 s; } z;
            #pragma unroll
            for (int d = 0; d < 4; ++d)
                z.u[d] = pk2bf(pf[kk][nt][2*d], pf[kk][nt][2*d + 1]);
            pb0[kk][nt] = z.s;
        }
    // NOTE: pf1 is issued AFTER this barrier. hipcc drains vmcnt(0) at every
    // s_barrier, so issuing it here would force-complete it at barrier 1 and
    // stall; issuing after the barrier lets it genuinely fly under stage A
    // and drain at barrier 2, where the pack consumes it.
    __syncthreads();

    // ---- issue point-1 pre loads (in flight for real under stage A) ----
    float pf1[2][2][8];
    #pragma unroll
    for (int kk = 0; kk < 2; ++kk)
        #pragma unroll
        for (int nt = 0; nt < 2; ++nt)
            #pragma unroll
            for (int j = 0; j < 8; ++j)
                pf1[kk][nt][j] = pbase1[(size_t)(kk*32 + g*8 + j)*131072 + nt*16 + lr];

    // ---------------- Stage A: h = relu(w1f @ f + sh1) -> P1/P2 (pf1 in flight) --------
    // With the prep-side row permutation each lane's 4 outputs are LDS-contiguous:
    // one packed uint2 (ds_write_b64) per ii instead of 4 scalar b16 stores.
    {
        short8 bf0 = *(const short8*)&smem[FBa(lr, g*8)];
        short8 bf1 = *(const short8*)&smem[FBa(lr, 32 + g*8)];
        const unsigned short* w1p = w1f + ((size_t)(w*32)*64 + l)*8;
        #pragma unroll 8
        for (int ii = 0; ii < 16; ++ii) {
            short8 a0 = *(const short8*)(w1p + (ii*2 + 0)*512);
            short8 a1 = *(const short8*)(w1p + (ii*2 + 1)*512);
            f32x4 acc = __builtin_amdgcn_mfma_f32_16x16x32_bf16(a0, bf0, zz4, 0, 0, 0);
            acc = __builtin_amdgcn_mfma_f32_16x16x32_bf16(a1, bf1, acc, 0, 0, 0);
            const int i = w*16 + ii;
            f32x4 shv = *(const f32x4*)(sh1 + i*16 + g*4);
            float h0 = fmaxf(acc[0] + shv[0], 0.f);
            float h1 = fmaxf(acc[1] + shv[1], 0.f);
            float h2 = fmaxf(acc[2] + shv[2], 0.f);
            float h3 = fmaxf(acc[3] + shv[3], 0.f);
            uint2 hv; hv.x = pk2bf(h0, h1); hv.y = pk2bf(h2, h3);
            if (w < 4) {
                // m = r*64 + c : r = i>>2, c = (i&3)*16 + g*4 .. +3  -> P1[r][c] contiguous
                *(uint2*)&smem[P1a(lr, i >> 2, (i & 3)*16 + g*4)] = hv;
            } else {
                // m = 1024 + c*16 + r : c = i-64, r = g*4 .. +3     -> P2[c][r] contiguous
                *(uint2*)&smem[P2a(lr, i - 64, g*4)] = hv;
            }
        }
    }
    // ---- pack point-1 -> pb1 (pf1 drains here, hidden by stage A above) ----
    #pragma unroll
    for (int kk = 0; kk < 2; ++kk)
        #pragma unroll
        for (int nt = 0; nt < 2; ++nt) {
            union { unsigned int u[4]; short8 s; } z;
            #pragma unroll
            for (int d = 0; d < 4; ++d)
                z.u[d] = pk2bf(pf1[kk][nt][2*d], pf1[kk][nt][2*d + 1]);
            pb1[kk][nt] = z.s;
        }
    __syncthreads();

    // ---------------- Stage B: 2 points per wave, compile-time unrolled ----------------
    {
        f32x4 l1g = *(const f32x4*)(ln1g + g*4);
        f32x4 l1b = *(const f32x4*)(ln1b + g*4);
        auto stageB = [&](int pt, const short8 (&pbx)[2][2]) {
            // GEMM1: t1^T[r][s] = p1^T[r][c] @ pre^T[c][s], K=64
            short8 a1f0 = *(const short8*)&smem[P1a(pt, lr, g*8)];
            short8 a1f1 = *(const short8*)&smem[P1a(pt, lr, 32 + g*8)];
            f32x4 acc1[2];
            #pragma unroll
            for (int nt = 0; nt < 2; ++nt) {
                f32x4 a = __builtin_amdgcn_mfma_f32_16x16x32_bf16(a1f0, pbx[0][nt], zz4, 0, 0, 0);
                acc1[nt] = __builtin_amdgcn_mfma_f32_16x16x32_bf16(a1f1, pbx[1][nt], a, 0, 0, 0);
            }
            // LN1 over r: in-lane 4 + shfl(16,32)
            #pragma unroll
            for (int nt = 0; nt < 2; ++nt) {
                float s0 = acc1[nt][0] + acc1[nt][1] + acc1[nt][2] + acc1[nt][3];
                float q0 = acc1[nt][0]*acc1[nt][0] + acc1[nt][1]*acc1[nt][1]
                         + acc1[nt][2]*acc1[nt][2] + acc1[nt][3]*acc1[nt][3];
                s0 += __shfl_xor(s0, 16); s0 += __shfl_xor(s0, 32);
                q0 += __shfl_xor(q0, 16); q0 += __shfl_xor(q0, 32);
                float mu = s0 * 0.0625f;
                float rs = rsqrtf(q0 * 0.0625f - mu*mu + EPSf);
                float v0 = fmaxf((acc1[nt][0] - mu)*rs*l1g[0] + l1b[0], 0.f);
                float v1 = fmaxf((acc1[nt][1] - mu)*rs*l1g[1] + l1b[1], 0.f);
                float v2 = fmaxf((acc1[nt][2] - mu)*rs*l1g[2] + l1b[2], 0.f);
                float v3 = fmaxf((acc1[nt][3] - mu)*rs*l1g[3] + l1b[3], 0.f);
                uint2 dd; dd.x = pk2bf(v0, v1); dd.y = pk2bf(v2, v3);
                *(uint2*)&smem[T1a(w, nt*16 + lr, g*4)] = dd;
            }
            // GEMM2 (32x32x16): t2^T[c][s] = p2^T[c][r] @ t1^T[r][s], K=16 exact
            short8 bt1  = *(const short8*)&smem[T1a(w, c32, hi*8)];
            short8 a2f0 = *(const short8*)&smem[P2a(pt, c32, hi*8)];
            short8 a2f1 = *(const short8*)&smem[P2a(pt, 32 + c32, hi*8)];
            f32x16 acc2a = __builtin_amdgcn_mfma_f32_32x32x16_bf16(a2f0, bt1, zz16, 0, 0, 0);
            f32x16 acc2b = __builtin_amdgcn_mfma_f32_32x32x16_bf16(a2f1, bt1, zz16, 0, 0, 0);
            // LN2 over c (64): in-lane 32 + one shfl(32) pair
            float sm2 = 0.f, sq2 = 0.f;
            #pragma unroll
            for (int e = 0; e < 16; ++e) { float v = acc2a[e]; sm2 += v; sq2 += v*v; }
            #pragma unroll
            for (int e = 0; e < 16; ++e) { float v = acc2b[e]; sm2 += v; sq2 += v*v; }
            sm2 += __shfl_xor(sm2, 32); sq2 += __shfl_xor(sq2, 32);
            float mu2 = sm2 * (1.0f/64.0f);
            float rs2 = rsqrtf(sq2 * (1.0f/64.0f) - mu2*mu2 + EPSf);
            // write FLAT[pt] (overlays P1/P2[pt]; same-wave in-order DS makes it safe)
            #pragma unroll
            for (int qh = 0; qh < 4; ++qh) {
                int c0 = qh*8 + hi*4;
                f32x4 gq = *(const f32x4*)(ln2g + c0);
                f32x4 bq = *(const f32x4*)(ln2b + c0);
                float t0 = fmaxf((acc2a[qh*4 + 0] - mu2)*rs2*gq[0] + bq[0], 0.f);
                float t1 = fmaxf((acc2a[qh*4 + 1] - mu2)*rs2*gq[1] + bq[1], 0.f);
                float t2 = fmaxf((acc2a[qh*4 + 2] - mu2)*rs2*gq[2] + bq[2], 0.f);
                float t3 = fmaxf((acc2a[qh*4 + 3] - mu2)*rs2*gq[3] + bq[3], 0.f);
                uint2 dd; dd.x = pk2bf(t0, t1); dd.y = pk2bf(t2, t3);
                *(uint2*)&smem[FTa(pt, c32*64 + c0)] = dd;
            }
            #pragma unroll
            for (int qh = 0; qh < 4; ++qh) {
                int c0 = 32 + qh*8 + hi*4;
                f32x4 gq = *(const f32x4*)(ln2g + c0);
                f32x4 bq = *(const f32x4*)(ln2b + c0);
                float t0 = fmaxf((acc2b[qh*4 + 0] - mu2)*rs2*gq[0] + bq[0], 0.f);
                float t1 = fmaxf((acc2b[qh*4 + 1] - mu2)*rs2*gq[1] + bq[1], 0.f);
                float t2 = fmaxf((acc2b[qh*4 + 2] - mu2)*rs2*gq[2] + bq[2], 0.f);
                float t3 = fmaxf((acc2b[qh*4 + 3] - mu2)*rs2*gq[3] + bq[3], 0.f);
                uint2 dd; dd.x = pk2bf(t0, t1); dd.y = pk2bf(t2, t3);
                *(uint2*)&smem[FTa(pt, c32*64 + c0)] = dd;
            }
        };
        stageB(w*2 + 0, pb0);
        stageB(w*2 + 1, pb1);
    }
    __syncthreads();

    // ---------------- Stage C: w2f @ flat, 2 k-halves x 4 m-tiles, dual acc chains ------
    {
        const int kh = w >> 2, mt = w & 3;
        f32x4 accA = zz4, accB = zz4;
        #pragma unroll 4
        for (int t = 0; t < 32; t += 2) {
            const int ks = kh*32 + t;
            short8 bfl0 = *(const short8*)&smem[FTa(lr, ks*32 + g*8)];
            short8 af0  = *(const short8*)(w2f + ((size_t)(ks*4 + mt)*64 + l)*8);
            short8 bfl1 = *(const short8*)&smem[FTa(lr, (ks+1)*32 + g*8)];
            short8 af1  = *(const short8*)(w2f + ((size_t)((ks+1)*4 + mt)*64 + l)*8);
            accA = __builtin_amdgcn_mfma_f32_16x16x32_bf16(af0, bfl0, accA, 0, 0, 0);
            accB = __builtin_amdgcn_mfma_f32_16x16x32_bf16(af1, bfl1, accB, 0, 0, 0);
        }
        f32x4 acc = accA + accB;
        *(f32x4*)&smem[PARTw(kh, mt, lr, g)] = acc;   // PART overlays T1 (dead)
    }
    __syncthreads();
    // reduce 2 partials; epilogue: relu(affine) + residual relu (2 points/thread)
    {
        const int ro = tid >> 3, rp = tid & 7;
        const int mt2 = ro >> 4, o16 = ro & 15;
        const float sh2v = sh2[ro];
        #pragma unroll
        for (int ph = 0; ph < 2; ++ph) {
            const int pt = rp + ph*8;
            float s = *(const float*)&smem[PARTr(0, mt2, pt, o16)]
                    + *(const float*)&smem[PARTr(1, mt2, pt, o16)];
            float y = fmaxf(s + sh2v, 0.f);
            size_t oidx = ((size_t)(b*64 + ro))*4096 + n0 + pt;
            out[oidx] = fmaxf(y + feat[oidx], 0.f);
        }
    }
}

extern "C" void kernel_launch(void* const* d_in, const int* in_sizes, int n_in,
                              void* d_out, int out_size, void* d_ws, size_t ws_size,
                              hipStream_t stream) {
    (void)in_sizes; (void)n_in; (void)out_size; (void)ws_size;
    const float* pre  = (const float*)d_in[0];
    const float* feat = (const float*)d_in[1];
    const float* w1   = (const float*)d_in[2];
    const float* bn1g = (const float*)d_in[3];
    const float* bn1b = (const float*)d_in[4];
    const float* bn1m = (const float*)d_in[5];
    const float* bn1v = (const float*)d_in[6];
    const float* ln1g = (const float*)d_in[7];
    const float* ln1b = (const float*)d_in[8];
    const float* ln2g = (const float*)d_in[9];
    const float* ln2b = (const float*)d_in[10];
    const float* w2   = (const float*)d_in[11];
    const float* bn2g = (const float*)d_in[12];
    const float* bn2b = (const float*)d_in[13];
    const float* bn2m = (const float*)d_in[14];
    const float* bn2v = (const float*)d_in[15];
    float* out = (float*)d_out;

    unsigned short* w1f = (unsigned short*)d_ws;          // 2048*64 bf16
    unsigned short* w2f = w1f + 2048*64;                  // 64*2048 bf16
    float* sh1 = (float*)(w2f + 64*2048);                 // 2048 f32 (permuted index)
    float* sh2 = sh1 + 2048;                              // 64 f32

    prep_kernel<<<512, 256, 0, stream>>>(w1, bn1g, bn1b, bn1m, bn1v,
                                         w2, bn2g, bn2b, bn2m, bn2v,
                                         w1f, w2f, sh1, sh2);
    dyn_mfma<<<2048, 512, 0, stream>>>(pre, feat, w1f, w2f, sh1, sh2,
                                       ln1g, ln1b, ln2g, ln2b, out);
}